// Round 5
// baseline (240.074 us; speedup 1.0000x reference)
//
#include <hip/hip_runtime.h>
#include <hip/hip_bf16.h>

// NARX forward via bf16 MFMA (16x16x32), points-as-N formulation, round 4.
// Round-3 design (duplicate feature columns folded into W_in, so layer-1
// B-fragment is a direct global load of x[t-1-c, g, 0:8]; no F LDS tile),
// with the __builtin_bit_cast compile error fixed via __builtin_memcpy.

typedef __attribute__((ext_vector_type(8))) short bf16x8;
typedef __attribute__((ext_vector_type(4))) float f32x4;

__device__ __forceinline__ unsigned pk2(float lo, float hi) {
    __hip_bfloat162 h = __float22bfloat162_rn(float2{lo, hi});
    unsigned u;
    __builtin_memcpy(&u, &h, 4);          // compiler emits v_cvt_pk_bf16_f32, memcpy is free
    return u;
}

union BF8 { bf16x8 v; unsigned u[4]; };

__global__ __launch_bounds__(256) void narx_mfma(
    const float* __restrict__ x, const float* __restrict__ W_in, const float* __restrict__ b_in,
    const float* __restrict__ W_ih, const float* __restrict__ b_ih, const float* __restrict__ b_hh,
    const float* __restrict__ W_out, const float* __restrict__ b_out, float* __restrict__ out)
{
    // Per-wave H tile only: 16 pts x 64 bf16, row padded to 72 (2-way banks = free).
    __shared__ unsigned short H[4][16][72];

    // bijective XCD-aware swizzle (m204): consecutive b share an XCD -> L2 reuse of x rows
    const int nwg  = gridDim.x;
    const int orig = blockIdx.x;
    const int q8 = nwg >> 3, r8 = nwg & 7;
    const int xcd = orig & 7, inner = orig >> 3;
    const int b = (xcd < r8 ? xcd * (q8 + 1) : r8 * (q8 + 1) + (xcd - r8) * q8) + inner;

    const int lane = threadIdx.x & 63;
    const int w    = threadIdx.x >> 6;   // wave 0..3
    const int c    = lane >> 4;          // K-chunk group 0..3
    const int pl   = lane & 15;          // point/row within 16-tile
    const int pt0  = 3072 + b * 512 + w * 128;   // wave's first flat point (t*1024+g)

    // ---- A-fragments: folded W' (64x32, cols 24..31 zero) ----
    // new-k 0..7  = x[t-1] ch0..7 : ch<7 -> W[:,ch]+W[:,21+ch]; ch7 -> W[:,28]+W[:,31]
    // new-k 8..15 = x[t-2] ch0..7 : ch<7 -> W[:,14+ch];          ch7 -> W[:,30]
    // new-k 16..23= x[t-3] ch0..7 : ch<7 -> W[:,7+ch];           ch7 -> W[:,29]
    bf16x8 wa[4];
    #pragma unroll
    for (int T = 0; T < 4; ++T) {
        const float* W = W_in + (16*T + pl) * 32;
        float wr[8];
        if (c == 0) {
            #pragma unroll
            for (int j = 0; j < 7; ++j) wr[j] = W[j] + W[21 + j];
            wr[7] = W[28] + W[31];
        } else if (c == 1) {
            #pragma unroll
            for (int j = 0; j < 7; ++j) wr[j] = W[14 + j];
            wr[7] = W[30];
        } else if (c == 2) {
            #pragma unroll
            for (int j = 0; j < 7; ++j) wr[j] = W[7 + j];
            wr[7] = W[29];
        } else {
            #pragma unroll
            for (int j = 0; j < 8; ++j) wr[j] = 0.0f;
        }
        BF8 tv;
        tv.u[0] = pk2(wr[0], wr[1]); tv.u[1] = pk2(wr[2], wr[3]);
        tv.u[2] = pk2(wr[4], wr[5]); tv.u[3] = pk2(wr[6], wr[7]);
        wa[T] = tv.v;
    }

    // W_ih A-fragments: A[row=pl][k = 32*k0 + 8c + j]
    bf16x8 wi[2][4];
    #pragma unroll
    for (int k0 = 0; k0 < 2; ++k0)
    #pragma unroll
    for (int U = 0; U < 4; ++U) {
        const float* p = W_ih + (16*U + pl) * 64 + 32*k0 + 8*c;
        float4 u0 = *(const float4*)p, u1 = *(const float4*)(p + 4);
        BF8 tv;
        tv.u[0] = pk2(u0.x, u0.y); tv.u[1] = pk2(u0.z, u0.w);
        tv.u[2] = pk2(u1.x, u1.y); tv.u[3] = pk2(u1.z, u1.w);
        wi[k0][U] = tv.v;
    }

    // per-lane bias / output-weight slices at h = 16T + 4c + q (C/D row layout)
    f32x4 bin[4], bias2[4], wo[4];
    #pragma unroll
    for (int T = 0; T < 4; ++T) {
        bin[T] = *(const f32x4*)(b_in + 16*T + 4*c);
        f32x4 bi = *(const f32x4*)(b_ih + 16*T + 4*c);
        f32x4 bh = *(const f32x4*)(b_hh + 16*T + 4*c);
        bias2[T] = bi + bh;
        wo[T] = *(const f32x4*)(W_out + 16*T + 4*c);
    }
    const float bout = b_out[0];

    #pragma unroll 2
    for (int rb = 0; rb < 8; ++rb) {
        const int m0 = pt0 + rb * 16;        // tile base (multiple of 16 -> no t crossing)
        const int t  = m0 >> 10, g0 = m0 & 1023;

        // ---- B1-fragment straight from global: lane (pl, c<3) reads x[t-1-c, g0+pl, 0:8] ----
        bf16x8 bf1;
        if (c < 3) {
            const float4* xr = (const float4*)x + ((size_t)(t - 1 - c) * 1024 + g0 + pl) * 2;
            float4 u0 = xr[0], u1 = xr[1];
            BF8 tv;
            tv.u[0] = pk2(u0.x, u0.y); tv.u[1] = pk2(u0.z, u0.w);
            tv.u[2] = pk2(u1.x, u1.y); tv.u[3] = pk2(u1.z, u1.w);
            bf1 = tv.v;
        } else {
            BF8 tv; tv.u[0] = tv.u[1] = tv.u[2] = tv.u[3] = 0u;
            bf1 = tv.v;
        }

        // ---- layer 1: D1 = W' . X  (+ b_in) ----
        f32x4 d1[4];
        #pragma unroll
        for (int T = 0; T < 4; ++T)
            d1[T] = __builtin_amdgcn_mfma_f32_16x16x32_bf16(wa[T], bf1, bin[T], 0, 0, 0);

        // relu -> bf16 -> H[pt][h]  (lane holds h = 16T+4c+q for pt = pl)
        #pragma unroll
        for (int T = 0; T < 4; ++T) {
            float h0 = fmaxf(d1[T][0], 0.f), h1 = fmaxf(d1[T][1], 0.f);
            float h2 = fmaxf(d1[T][2], 0.f), h3 = fmaxf(d1[T][3], 0.f);
            *(uint2*)&H[w][pl][16*T + 4*c] = make_uint2(pk2(h0, h1), pk2(h2, h3));
        }
        asm volatile("s_waitcnt lgkmcnt(0)" ::: "memory");   // cross-lane dep within wave
        __builtin_amdgcn_sched_barrier(0);

        // B2-fragments: lane (pl, c) reads H[pt=pl][k = 8c+j (+32)]
        bf16x8 bh0 = *(bf16x8*)&H[w][pl][8*c];
        bf16x8 bh1 = *(bf16x8*)&H[w][pl][32 + 8*c];

        f32x4 d2[4];
        #pragma unroll
        for (int U = 0; U < 4; ++U) {
            d2[U] = __builtin_amdgcn_mfma_f32_16x16x32_bf16(wi[0][U], bh0, bias2[U], 0, 0, 0);
            d2[U] = __builtin_amdgcn_mfma_f32_16x16x32_bf16(wi[1][U], bh1, d2[U],   0, 0, 0);
        }
        asm volatile("s_waitcnt lgkmcnt(0)" ::: "memory");   // reads done before next rb's writes
        __builtin_amdgcn_sched_barrier(0);

        // Pade(5,4) tanh (clamp +-4, max err ~2.3e-3) + W_out dot
        float part = 0.f;
        #pragma unroll
        for (int U = 0; U < 4; ++U) {
            #pragma unroll
            for (int j = 0; j < 4; ++j) {
                float z  = fminf(fmaxf(d2[U][j], -4.f), 4.f);   // v_med3
                float p2 = z * z;
                float num = z * fmaf(p2, p2 + 105.f, 945.f);
                float den = fmaf(p2, fmaf(p2, 15.f, 420.f), 945.f);
                part = fmaf(wo[U][j], num * __builtin_amdgcn_rcpf(den), part);
            }
        }
        // reduce partials across the 4 c-groups (same pt at lanes pl, pl+16, pl+32, pl+48)
        part += __shfl_xor(part, 16);
        part += __shfl_xor(part, 32);
        if (lane < 16)
            out[m0 + lane] = part + bout;
    }
}

__global__ __launch_bounds__(256) void narx_pass(const float* __restrict__ x, float* __restrict__ out) {
    const int i = blockIdx.x * 256 + threadIdx.x;   // i < 3072
    out[i] = x[i * 8 + 7];
}

extern "C" void kernel_launch(void* const* d_in, const int* in_sizes, int n_in,
                              void* d_out, int out_size, void* d_ws, size_t ws_size,
                              hipStream_t stream) {
    const float* x     = (const float*)d_in[0];
    const float* W_in  = (const float*)d_in[1];
    const float* b_in  = (const float*)d_in[2];
    const float* W_ih  = (const float*)d_in[3];
    const float* b_ih  = (const float*)d_in[4];
    // d_in[5] = W_hh: unused in the reference forward
    const float* b_hh  = (const float*)d_in[6];
    const float* W_out = (const float*)d_in[7];
    const float* b_out = (const float*)d_in[8];
    float* out = (float*)d_out;

    // points m in [3072, 4096*1024): 4,191,232 = 8186 blocks * 512 pts
    narx_mfma<<<8186, 256, 0, stream>>>(x, W_in, b_in, W_ih, b_ih, b_hh, W_out, b_out, out);
    narx_pass<<<12, 256, 0, stream>>>(x, out);      // t < 3 passthrough
}

// Round 6
// 196.279 us; speedup vs baseline: 1.2231x; 1.2231x over previous
//
#include <hip/hip_runtime.h>
#include <hip/hip_bf16.h>

// NARX forward via bf16 MFMA (16x16x32), round 6.
// Round-5 diagnosis: compiler rematerialized the prepped weight fragments
// every tile (VGPR=72 < ~96 invariant regs needed). Fix: pin fragments with
// opaque asm ("+v"), raise budget via __launch_bounds__(256,3), and fold
// b_in into W' k=24 column (c==3 lanes feed feature 1.0).

typedef __attribute__((ext_vector_type(8))) short bf16x8;
typedef __attribute__((ext_vector_type(4))) float f32x4;

__device__ __forceinline__ unsigned pk2(float lo, float hi) {
    __hip_bfloat162 h = __float22bfloat162_rn(float2{lo, hi});
    unsigned u;
    __builtin_memcpy(&u, &h, 4);          // v_cvt_pk_bf16_f32; memcpy is free
    return u;
}

union BF8 { bf16x8 v; unsigned u[4]; };

__global__ __launch_bounds__(256, 3) void narx_mfma(
    const float* __restrict__ x, const float* __restrict__ W_in, const float* __restrict__ b_in,
    const float* __restrict__ W_ih, const float* __restrict__ b_ih, const float* __restrict__ b_hh,
    const float* __restrict__ W_out, const float* __restrict__ b_out, float* __restrict__ out)
{
    // Per-wave H tile: 16 pts x 64 bf16, row padded to 72 (2-way banks = free).
    __shared__ unsigned short H[4][16][72];

    // bijective XCD-aware swizzle (m204): consecutive b share an XCD -> L2 reuse of x rows
    const int nwg  = gridDim.x;
    const int orig = blockIdx.x;
    const int q8 = nwg >> 3, r8 = nwg & 7;
    const int xcd = orig & 7, inner = orig >> 3;
    const int b = (xcd < r8 ? xcd * (q8 + 1) : r8 * (q8 + 1) + (xcd - r8) * q8) + inner;

    const int lane = threadIdx.x & 63;
    const int w    = threadIdx.x >> 6;   // wave 0..3
    const int c    = lane >> 4;          // K-chunk group 0..3
    const int pl   = lane & 15;          // point/row within 16-tile
    const int pt0  = 3072 + b * 512 + w * 128;   // wave's first flat point (t*1024+g)

    // ---- A-fragments: folded W' (64x32), bias in k=24 column ----
    // k 0..7  = x[t-1] ch: ch<7 -> W[:,ch]+W[:,21+ch]; ch7 -> W[:,28]+W[:,31]
    // k 8..15 = x[t-2] ch: ch<7 -> W[:,14+ch];          ch7 -> W[:,30]
    // k 16..23= x[t-3] ch: ch<7 -> W[:,7+ch];           ch7 -> W[:,29]
    // k 24    = b_in (feature 1.0), k 25..31 = 0
    bf16x8 wa[4];
    #pragma unroll
    for (int T = 0; T < 4; ++T) {
        const float* W = W_in + (16*T + pl) * 32;
        float wr[8];
        if (c == 0) {
            #pragma unroll
            for (int j = 0; j < 7; ++j) wr[j] = W[j] + W[21 + j];
            wr[7] = W[28] + W[31];
        } else if (c == 1) {
            #pragma unroll
            for (int j = 0; j < 7; ++j) wr[j] = W[14 + j];
            wr[7] = W[30];
        } else if (c == 2) {
            #pragma unroll
            for (int j = 0; j < 7; ++j) wr[j] = W[7 + j];
            wr[7] = W[29];
        } else {
            wr[0] = b_in[16*T + pl];
            #pragma unroll
            for (int j = 1; j < 8; ++j) wr[j] = 0.0f;
        }
        BF8 tv;
        tv.u[0] = pk2(wr[0], wr[1]); tv.u[1] = pk2(wr[2], wr[3]);
        tv.u[2] = pk2(wr[4], wr[5]); tv.u[3] = pk2(wr[6], wr[7]);
        wa[T] = tv.v;
    }

    // W_ih A-fragments: A[row=pl][k = 32*k0 + 8c + j]
    bf16x8 wi[2][4];
    #pragma unroll
    for (int k0 = 0; k0 < 2; ++k0)
    #pragma unroll
    for (int U = 0; U < 4; ++U) {
        const float* p = W_ih + (16*U + pl) * 64 + 32*k0 + 8*c;
        float4 u0 = *(const float4*)p, u1 = *(const float4*)(p + 4);
        BF8 tv;
        tv.u[0] = pk2(u0.x, u0.y); tv.u[1] = pk2(u0.z, u0.w);
        tv.u[2] = pk2(u1.x, u1.y); tv.u[3] = pk2(u1.z, u1.w);
        wi[k0][U] = tv.v;
    }

    // per-lane bias / output-weight slices at h = 16U + 4c + q (C/D row layout)
    f32x4 bias2[4], wo[4];
    #pragma unroll
    for (int U = 0; U < 4; ++U) {
        f32x4 bi = *(const f32x4*)(b_ih + 16*U + 4*c);
        f32x4 bh = *(const f32x4*)(b_hh + 16*U + 4*c);
        bias2[U] = bi + bh;
        wo[U] = *(const f32x4*)(W_out + 16*U + 4*c);
    }
    const float bout = b_out[0];

    // Pin the prepped invariants: opaque to the optimizer -> cannot be
    // rematerialized per tile; with the (256,3) budget they stay in VGPRs.
    asm volatile("" : "+v"(wa[0]), "+v"(wa[1]), "+v"(wa[2]), "+v"(wa[3]),
                      "+v"(wi[0][0]), "+v"(wi[0][1]), "+v"(wi[0][2]), "+v"(wi[0][3]),
                      "+v"(wi[1][0]), "+v"(wi[1][1]), "+v"(wi[1][2]), "+v"(wi[1][3]),
                      "+v"(bias2[0]), "+v"(bias2[1]), "+v"(bias2[2]), "+v"(bias2[3]),
                      "+v"(wo[0]), "+v"(wo[1]), "+v"(wo[2]), "+v"(wo[3]));

    const f32x4 zero = {0.f, 0.f, 0.f, 0.f};

    #pragma unroll 2
    for (int rb = 0; rb < 8; ++rb) {
        const int m0 = pt0 + rb * 16;        // tile base (16-aligned -> single t per tile)
        const int t  = m0 >> 10, g0 = m0 & 1023;

        // ---- B1-fragment: lane (pl, c<3) reads x[t-1-c, g0+pl, 0:8]; c==3 -> bias feature ----
        bf16x8 bf1;
        if (c < 3) {
            const float4* xr = (const float4*)x + ((size_t)(t - 1 - c) * 1024 + g0 + pl) * 2;
            float4 u0 = xr[0], u1 = xr[1];
            BF8 tv;
            tv.u[0] = pk2(u0.x, u0.y); tv.u[1] = pk2(u0.z, u0.w);
            tv.u[2] = pk2(u1.x, u1.y); tv.u[3] = pk2(u1.z, u1.w);
            bf1 = tv.v;
        } else {
            BF8 tv;
            tv.u[0] = 0x00003f80u;           // bf16 1.0 at k=24
            tv.u[1] = tv.u[2] = tv.u[3] = 0u;
            bf1 = tv.v;
        }

        // ---- layer 1: D1 = W' . X  (bias via k=24) ----
        f32x4 d1[4];
        #pragma unroll
        for (int T = 0; T < 4; ++T)
            d1[T] = __builtin_amdgcn_mfma_f32_16x16x32_bf16(wa[T], bf1, zero, 0, 0, 0);

        // relu -> bf16 -> H[pt][h]  (lane holds h = 16T+4c+q for pt = pl)
        #pragma unroll
        for (int T = 0; T < 4; ++T) {
            float h0 = fmaxf(d1[T][0], 0.f), h1 = fmaxf(d1[T][1], 0.f);
            float h2 = fmaxf(d1[T][2], 0.f), h3 = fmaxf(d1[T][3], 0.f);
            *(uint2*)&H[w][pl][16*T + 4*c] = make_uint2(pk2(h0, h1), pk2(h2, h3));
        }
        asm volatile("s_waitcnt lgkmcnt(0)" ::: "memory");   // cross-lane dep within wave
        __builtin_amdgcn_sched_barrier(0);

        // B2-fragments: lane (pl, c) reads H[pt=pl][k = 8c+j (+32)]
        bf16x8 bh0 = *(bf16x8*)&H[w][pl][8*c];
        bf16x8 bh1 = *(bf16x8*)&H[w][pl][32 + 8*c];

        f32x4 d2[4];
        #pragma unroll
        for (int U = 0; U < 4; ++U) {
            d2[U] = __builtin_amdgcn_mfma_f32_16x16x32_bf16(wi[0][U], bh0, bias2[U], 0, 0, 0);
            d2[U] = __builtin_amdgcn_mfma_f32_16x16x32_bf16(wi[1][U], bh1, d2[U],   0, 0, 0);
        }
        asm volatile("s_waitcnt lgkmcnt(0)" ::: "memory");   // reads done before next rb's writes
        __builtin_amdgcn_sched_barrier(0);

        // Pade(5,4) tanh (clamp +-4, max err ~2.3e-3) + W_out dot
        float part = 0.f;
        #pragma unroll
        for (int U = 0; U < 4; ++U) {
            #pragma unroll
            for (int j = 0; j < 4; ++j) {
                float z  = fminf(fmaxf(d2[U][j], -4.f), 4.f);   // v_med3
                float p2 = z * z;
                float num = z * fmaf(p2, p2 + 105.f, 945.f);
                float den = fmaf(p2, fmaf(p2, 15.f, 420.f), 945.f);
                part = fmaf(wo[U][j], num * __builtin_amdgcn_rcpf(den), part);
            }
        }
        // reduce partials across the 4 c-groups (same pt at lanes pl, pl+16, pl+32, pl+48)
        part += __shfl_xor(part, 16);
        part += __shfl_xor(part, 32);
        if (lane < 16)
            out[m0 + lane] = part + bout;
    }
}

__global__ __launch_bounds__(256) void narx_pass(const float* __restrict__ x, float* __restrict__ out) {
    const int i = blockIdx.x * 256 + threadIdx.x;   // i < 3072
    out[i] = x[i * 8 + 7];
}

extern "C" void kernel_launch(void* const* d_in, const int* in_sizes, int n_in,
                              void* d_out, int out_size, void* d_ws, size_t ws_size,
                              hipStream_t stream) {
    const float* x     = (const float*)d_in[0];
    const float* W_in  = (const float*)d_in[1];
    const float* b_in  = (const float*)d_in[2];
    const float* W_ih  = (const float*)d_in[3];
    const float* b_ih  = (const float*)d_in[4];
    // d_in[5] = W_hh: unused in the reference forward
    const float* b_hh  = (const float*)d_in[6];
    const float* W_out = (const float*)d_in[7];
    const float* b_out = (const float*)d_in[8];
    float* out = (float*)d_out;

    // points m in [3072, 4096*1024): 4,191,232 = 8186 blocks * 512 pts
    narx_mfma<<<8186, 256, 0, stream>>>(x, W_in, b_in, W_ih, b_ih, b_hh, W_out, b_out, out);
    narx_pass<<<12, 256, 0, stream>>>(x, out);      // t < 3 passthrough
}

// Round 8
// 160.824 us; speedup vs baseline: 1.4928x; 1.2205x over previous
//
#include <hip/hip_runtime.h>
#include <hip/hip_bf16.h>

// NARX forward via bf16 MFMA (16x16x32), round 8.
//  - FIX round-7 OOB: F read row is local (rb*16+pl), F rebuilt per 64-pt half.
//  - Weight fragments precomputed ONCE into d_ws by a prep kernel (per-lane
//    final fragment layout). Main kernel prep = 16 coalesced dwordx4 loads;
//    no fold/convert chains to rematerialize, no asm pins needed.
//  - H double-buffered by rb parity -> one lgkm drain per tile (was two).

typedef __attribute__((ext_vector_type(8))) short bf16x8;
typedef __attribute__((ext_vector_type(4))) float f32x4;

__device__ __forceinline__ unsigned pk2(float lo, float hi) {
    __hip_bfloat162 h = __float22bfloat162_rn(float2{lo, hi});
    unsigned u; __builtin_memcpy(&u, &h, 4);   // v_cvt_pk_bf16_f32 path; memcpy is free
    return u;
}

union BF8 { bf16x8 v; unsigned u[4]; uint4 q; };

// d_ws layout in uint4 (16B) units:
//   [0,256)     WA[lane][T]      bf16x8   (folded W_in', bias col at k=24)
//   [256,768)   WI[lane][k0][U]  bf16x8
//   [768,1024)  B2[lane][U]      float4   (b_ih + b_hh slice)
//   [1024,1280) WO[lane][U]      float4   (W_out slice)

__global__ __launch_bounds__(64) void narx_prep(
    const float* __restrict__ W_in, const float* __restrict__ b_in,
    const float* __restrict__ W_ih, const float* __restrict__ b_ih,
    const float* __restrict__ b_hh, const float* __restrict__ W_out,
    uint4* __restrict__ ws)
{
    const int lane = threadIdx.x;        // 64 threads, one wave
    const int c = lane >> 4, pl = lane & 15;

    // Folded W' (64x32): k0..7 = x[t-1] ch0..7, k8..15 = x[t-2], k16..23 = x[t-3],
    // k24 = b_in (feature 1.0), k25..31 = 0.
    #pragma unroll
    for (int T = 0; T < 4; ++T) {
        const float* W = W_in + (16*T + pl) * 32;
        float wr[8];
        if (c == 0) {
            #pragma unroll
            for (int j = 0; j < 7; ++j) wr[j] = W[j] + W[21 + j];
            wr[7] = W[28] + W[31];
        } else if (c == 1) {
            #pragma unroll
            for (int j = 0; j < 7; ++j) wr[j] = W[14 + j];
            wr[7] = W[30];
        } else if (c == 2) {
            #pragma unroll
            for (int j = 0; j < 7; ++j) wr[j] = W[7 + j];
            wr[7] = W[29];
        } else {
            wr[0] = b_in[16*T + pl];
            #pragma unroll
            for (int j = 1; j < 8; ++j) wr[j] = 0.0f;
        }
        BF8 t;
        t.u[0] = pk2(wr[0], wr[1]); t.u[1] = pk2(wr[2], wr[3]);
        t.u[2] = pk2(wr[4], wr[5]); t.u[3] = pk2(wr[6], wr[7]);
        ws[lane*4 + T] = t.q;
    }

    // W_ih fragments: A[row=16U+pl][k = 32*k0 + 8c + j]
    #pragma unroll
    for (int k0 = 0; k0 < 2; ++k0)
    #pragma unroll
    for (int U = 0; U < 4; ++U) {
        const float* p = W_ih + (16*U + pl) * 64 + 32*k0 + 8*c;
        float4 u0 = *(const float4*)p, u1 = *(const float4*)(p + 4);
        BF8 t;
        t.u[0] = pk2(u0.x, u0.y); t.u[1] = pk2(u0.z, u0.w);
        t.u[2] = pk2(u1.x, u1.y); t.u[3] = pk2(u1.z, u1.w);
        ws[256 + lane*8 + k0*4 + U] = t.q;
    }

    // bias2 / wo per-lane slices at h = 16U + 4c + q
    float4* wsf = (float4*)ws;
    #pragma unroll
    for (int U = 0; U < 4; ++U) {
        const int o = 16*U + 4*c;
        wsf[768  + lane*4 + U] = make_float4(b_ih[o+0]+b_hh[o+0], b_ih[o+1]+b_hh[o+1],
                                             b_ih[o+2]+b_hh[o+2], b_ih[o+3]+b_hh[o+3]);
        wsf[1024 + lane*4 + U] = make_float4(W_out[o+0], W_out[o+1], W_out[o+2], W_out[o+3]);
    }
}

__global__ __launch_bounds__(256, 3) void narx_main(
    const float* __restrict__ x, const uint4* __restrict__ ws,
    const float* __restrict__ b_out, float* __restrict__ out)
{
    // Per-wave scratch. F: 64 pts x 32 bf16 (16B-chunk XOR swizzle).
    // H: rb-parity double buffer, 16 pts x 64 bf16, row stride 72.
    __shared__ unsigned short F[4][64][32];
    __shared__ unsigned short H[4][2][16][72];

    // bijective XCD-aware swizzle (m204)
    const int nwg  = gridDim.x;
    const int orig = blockIdx.x;
    const int q8 = nwg >> 3, r8 = nwg & 7;
    const int xcd = orig & 7, inner = orig >> 3;
    const int b = (xcd < r8 ? xcd * (q8 + 1) : r8 * (q8 + 1) + (xcd - r8) * q8) + inner;

    const int lane = threadIdx.x & 63;
    const int w    = threadIdx.x >> 6;
    const int c    = lane >> 4;
    const int pl   = lane & 15;
    const int pt0  = 3072 + b * 512 + w * 128;

    // ---- fragment loads (coalesced, L2-hot; cheap to re-issue if spilled) ----
    bf16x8 wa[4];
    #pragma unroll
    for (int T = 0; T < 4; ++T) { BF8 t; t.q = ws[lane*4 + T]; wa[T] = t.v; }
    bf16x8 wi[2][4];
    #pragma unroll
    for (int k0 = 0; k0 < 2; ++k0)
    #pragma unroll
    for (int U = 0; U < 4; ++U) { BF8 t; t.q = ws[256 + lane*8 + k0*4 + U]; wi[k0][U] = t.v; }
    const float4* wsf = (const float4*)ws;
    f32x4 bias2[4], wo[4];
    #pragma unroll
    for (int U = 0; U < 4; ++U) {
        float4 v = wsf[768 + lane*4 + U];
        bias2[U] = f32x4{v.x, v.y, v.z, v.w};
        float4 u = wsf[1024 + lane*4 + U];
        wo[U] = f32x4{u.x, u.y, u.z, u.w};
    }
    const float bout = b_out[0];
    const f32x4 zero = {0.f, 0.f, 0.f, 0.f};
    const int s_rd = (pl >> 1) & 3;

    #pragma unroll 1
    for (int half = 0; half < 2; ++half) {
        // ---- build 64 feature rows (1 pt per lane): 3 raw x rows + bias chunk ----
        {
            const int p = pt0 + half * 64 + lane;
            const int t = p >> 10, g = p & 1023;
            const float4* xr = (const float4*)x;
            const size_t r1 = ((size_t)(t - 1) * 1024 + g) * 2;
            const size_t r2 = ((size_t)(t - 2) * 1024 + g) * 2;
            const size_t r3 = ((size_t)(t - 3) * 1024 + g) * 2;
            float4 a0 = xr[r1], a1 = xr[r1 + 1];
            float4 b0 = xr[r2], b1 = xr[r2 + 1];
            float4 c0 = xr[r3], c1 = xr[r3 + 1];
            uint4 q0 = make_uint4(pk2(a0.x,a0.y), pk2(a0.z,a0.w), pk2(a1.x,a1.y), pk2(a1.z,a1.w));
            uint4 q1 = make_uint4(pk2(b0.x,b0.y), pk2(b0.z,b0.w), pk2(b1.x,b1.y), pk2(b1.z,b1.w));
            uint4 q2 = make_uint4(pk2(c0.x,c0.y), pk2(c0.z,c0.w), pk2(c1.x,c1.y), pk2(c1.z,c1.w));
            uint4 q3 = make_uint4(0x00003f80u, 0u, 0u, 0u);   // bf16 1.0 at k=24
            const int s = (lane >> 1) & 3;
            uint4* Frow = (uint4*)&F[w][lane][0];
            Frow[0 ^ s] = q0; Frow[1 ^ s] = q1; Frow[2 ^ s] = q2; Frow[3 ^ s] = q3;
        }
        asm volatile("s_waitcnt lgkmcnt(0)" ::: "memory");   // cross-lane LDS dep within wave
        __builtin_amdgcn_sched_barrier(0);

        #pragma unroll 2
        for (int rb = 0; rb < 4; ++rb) {
            const int m0 = pt0 + half * 64 + rb * 16;

            // B1-fragment: LOCAL row rb*16+pl (round-7 bug: used half*64 offset -> OOB)
            bf16x8 bf1 = *(bf16x8*)&F[w][rb*16 + pl][(c ^ s_rd) * 8];

            f32x4 d1[4];
            #pragma unroll
            for (int T = 0; T < 4; ++T)
                d1[T] = __builtin_amdgcn_mfma_f32_16x16x32_bf16(wa[T], bf1, zero, 0, 0, 0);

            // relu -> bf16 -> H[parity][pt=pl][h=16T+4c+q]
            #pragma unroll
            for (int T = 0; T < 4; ++T) {
                float h0 = fmaxf(d1[T][0], 0.f), h1 = fmaxf(d1[T][1], 0.f);
                float h2 = fmaxf(d1[T][2], 0.f), h3 = fmaxf(d1[T][3], 0.f);
                *(uint2*)&H[w][rb & 1][pl][16*T + 4*c] = make_uint2(pk2(h0, h1), pk2(h2, h3));
            }
            asm volatile("s_waitcnt lgkmcnt(0)" ::: "memory");
            __builtin_amdgcn_sched_barrier(0);

            // B2-fragments from parity buffer (no post-read drain needed)
            bf16x8 bh0 = *(bf16x8*)&H[w][rb & 1][pl][8*c];
            bf16x8 bh1 = *(bf16x8*)&H[w][rb & 1][pl][32 + 8*c];

            f32x4 d2[4];
            #pragma unroll
            for (int U = 0; U < 4; ++U) {
                d2[U] = __builtin_amdgcn_mfma_f32_16x16x32_bf16(wi[0][U], bh0, bias2[U], 0, 0, 0);
                d2[U] = __builtin_amdgcn_mfma_f32_16x16x32_bf16(wi[1][U], bh1, d2[U],   0, 0, 0);
            }

            // Pade(5,4) tanh (clamp +-4, max err ~2.3e-3) + W_out dot
            float part = 0.f;
            #pragma unroll
            for (int U = 0; U < 4; ++U) {
                #pragma unroll
                for (int j = 0; j < 4; ++j) {
                    float z  = fminf(fmaxf(d2[U][j], -4.f), 4.f);
                    float p2 = z * z;
                    float num = z * fmaf(p2, p2 + 105.f, 945.f);
                    float den = fmaf(p2, fmaf(p2, 15.f, 420.f), 945.f);
                    part = fmaf(wo[U][j], num * __builtin_amdgcn_rcpf(den), part);
                }
            }
            part += __shfl_xor(part, 16);
            part += __shfl_xor(part, 32);
            if (lane < 16)
                out[m0 + lane] = part + bout;
        }
    }
}

__global__ __launch_bounds__(256) void narx_pass(const float* __restrict__ x, float* __restrict__ out) {
    const int i = blockIdx.x * 256 + threadIdx.x;   // i < 3072
    out[i] = x[i * 8 + 7];
}

extern "C" void kernel_launch(void* const* d_in, const int* in_sizes, int n_in,
                              void* d_out, int out_size, void* d_ws, size_t ws_size,
                              hipStream_t stream) {
    const float* x     = (const float*)d_in[0];
    const float* W_in  = (const float*)d_in[1];
    const float* b_in  = (const float*)d_in[2];
    const float* W_ih  = (const float*)d_in[3];
    const float* b_ih  = (const float*)d_in[4];
    // d_in[5] = W_hh: unused in the reference forward
    const float* b_hh  = (const float*)d_in[6];
    const float* W_out = (const float*)d_in[7];
    const float* b_out = (const float*)d_in[8];
    float* out = (float*)d_out;
    uint4* ws = (uint4*)d_ws;            // needs 20.5 KB

    narx_prep<<<1, 64, 0, stream>>>(W_in, b_in, W_ih, b_ih, b_hh, W_out, ws);
    // points m in [3072, 4096*1024): 4,191,232 = 8186 blocks * 512 pts
    narx_main<<<8186, 256, 0, stream>>>(x, ws, b_out, out);
    narx_pass<<<12, 256, 0, stream>>>(x, out);      // t < 3 passthrough
}

// Round 9
// 150.239 us; speedup vs baseline: 1.5979x; 1.0705x over previous
//
#include <hip/hip_runtime.h>
#include <hip/hip_bf16.h>

// NARX forward via bf16 MFMA (16x16x32), round 9.
// Key change: W_in rows are PERMUTED (prep kernel) so that layer-1's MFMA
// accumulator registers at lane (c,pl) are exactly layer-2's B-fragment
// (h in [8c,8c+8) and [8c+32,8c+40) for point pl). The H LDS tile, its
// ds_write/ds_read, the per-tile lgkm drain, and the 6.29M bank conflicts
// (all H-attributed: bit-identical across R2/R5/R6/R8) are deleted.
// tanh Pade is vectorized on f32x4 (v_pk_fma_f32 path), clamp via v_med3.

typedef __attribute__((ext_vector_type(8))) short bf16x8;
typedef __attribute__((ext_vector_type(4))) float f32x4;

__device__ __forceinline__ unsigned pk2(float lo, float hi) {
    __hip_bfloat162 h = __float22bfloat162_rn(float2{lo, hi});
    unsigned u; __builtin_memcpy(&u, &h, 4);   // v_cvt_pk_bf16_f32; memcpy is free
    return u;
}

union BF8 { bf16x8 v; unsigned u[4]; uint4 q; };

// d_ws layout in uint4 (16B) units:
//   [0,256)     WA[lane][T]      bf16x8  (folded W_in', sigma-permuted rows, bias col k=24)
//   [256,768)   WI[lane][k0][U]  bf16x8  (W_ih, natural)
//   [768,1024)  B2[lane][U]      float4  (b_ih + b_hh slice)
//   [1024,1280) WO[lane][U]      float4  (W_out slice)

__global__ __launch_bounds__(64) void narx_prep(
    const float* __restrict__ W_in, const float* __restrict__ b_in,
    const float* __restrict__ W_ih, const float* __restrict__ b_ih,
    const float* __restrict__ b_hh, const float* __restrict__ W_out,
    uint4* __restrict__ ws)
{
    const int lane = threadIdx.x;        // 64 threads, one wave
    const int c = lane >> 4, pl = lane & 15;

    // Folded W' (64x32): k0..7 = x[t-1] ch0..7, k8..15 = x[t-2], k16..23 = x[t-3],
    // k24 = bias (feature 1.0), k25..31 = 0.
    // Row permutation sigma: A-tile T, tile-row pl sources W_in row
    //   r = 8*(pl>>2) + (pl&3) + 4*(T&1) + 32*(T>>1)
    // so that D1 reg (T,q) at lane c holds h_{8c + 4*(T&1) + q + 32*(T>>1)}:
    // exactly the layer-2 B-fragment (bh0 from T=0,1; bh1 from T=2,3).
    #pragma unroll
    for (int T = 0; T < 4; ++T) {
        const int r = ((pl >> 2) * 8) + (pl & 3) + (T & 1) * 4 + (T >> 1) * 32;
        const float* W = W_in + r * 32;
        float wr[8];
        if (c == 0) {
            #pragma unroll
            for (int j = 0; j < 7; ++j) wr[j] = W[j] + W[21 + j];
            wr[7] = W[28] + W[31];
        } else if (c == 1) {
            #pragma unroll
            for (int j = 0; j < 7; ++j) wr[j] = W[14 + j];
            wr[7] = W[30];
        } else if (c == 2) {
            #pragma unroll
            for (int j = 0; j < 7; ++j) wr[j] = W[7 + j];
            wr[7] = W[29];
        } else {
            wr[0] = b_in[r];
            #pragma unroll
            for (int j = 1; j < 8; ++j) wr[j] = 0.0f;
        }
        BF8 t;
        t.u[0] = pk2(wr[0], wr[1]); t.u[1] = pk2(wr[2], wr[3]);
        t.u[2] = pk2(wr[4], wr[5]); t.u[3] = pk2(wr[6], wr[7]);
        ws[lane*4 + T] = t.q;
    }

    // W_ih fragments (natural): A[row=16U+pl][k = 32*k0 + 8c + j]
    #pragma unroll
    for (int k0 = 0; k0 < 2; ++k0)
    #pragma unroll
    for (int U = 0; U < 4; ++U) {
        const float* p = W_ih + (16*U + pl) * 64 + 32*k0 + 8*c;
        float4 u0 = *(const float4*)p, u1 = *(const float4*)(p + 4);
        BF8 t;
        t.u[0] = pk2(u0.x, u0.y); t.u[1] = pk2(u0.z, u0.w);
        t.u[2] = pk2(u1.x, u1.y); t.u[3] = pk2(u1.z, u1.w);
        ws[256 + lane*8 + k0*4 + U] = t.q;
    }

    // bias2 / wo per-lane slices at h = 16U + 4c + q
    float4* wsf = (float4*)ws;
    #pragma unroll
    for (int U = 0; U < 4; ++U) {
        const int o = 16*U + 4*c;
        wsf[768  + lane*4 + U] = make_float4(b_ih[o+0]+b_hh[o+0], b_ih[o+1]+b_hh[o+1],
                                             b_ih[o+2]+b_hh[o+2], b_ih[o+3]+b_hh[o+3]);
        wsf[1024 + lane*4 + U] = make_float4(W_out[o+0], W_out[o+1], W_out[o+2], W_out[o+3]);
    }
}

__global__ __launch_bounds__(256, 3) void narx_main(
    const float* __restrict__ x, const uint4* __restrict__ ws,
    const float* __restrict__ b_out, float* __restrict__ out)
{
    // Per-wave scratch: F only. 64 pts x 32 bf16, 16B-chunk XOR swizzle (conflict-free).
    __shared__ unsigned short F[4][64][32];

    // bijective XCD-aware swizzle (m204)
    const int nwg  = gridDim.x;
    const int orig = blockIdx.x;
    const int q8 = nwg >> 3, r8 = nwg & 7;
    const int xcd = orig & 7, inner = orig >> 3;
    const int b = (xcd < r8 ? xcd * (q8 + 1) : r8 * (q8 + 1) + (xcd - r8) * q8) + inner;

    const int lane = threadIdx.x & 63;
    const int w    = threadIdx.x >> 6;
    const int c    = lane >> 4;
    const int pl   = lane & 15;
    const int pt0  = 3072 + b * 512 + w * 128;

    // ---- fragment loads (coalesced, L2-hot) ----
    bf16x8 wa[4];
    #pragma unroll
    for (int T = 0; T < 4; ++T) { BF8 t; t.q = ws[lane*4 + T]; wa[T] = t.v; }
    bf16x8 wi[2][4];
    #pragma unroll
    for (int k0 = 0; k0 < 2; ++k0)
    #pragma unroll
    for (int U = 0; U < 4; ++U) { BF8 t; t.q = ws[256 + lane*8 + k0*4 + U]; wi[k0][U] = t.v; }
    const float4* wsf = (const float4*)ws;
    f32x4 bias2[4], wo[4];
    #pragma unroll
    for (int U = 0; U < 4; ++U) {
        float4 v = wsf[768 + lane*4 + U];
        bias2[U] = f32x4{v.x, v.y, v.z, v.w};
        float4 u = wsf[1024 + lane*4 + U];
        wo[U] = f32x4{u.x, u.y, u.z, u.w};
    }
    const float bout = b_out[0];
    const f32x4 zero = {0.f, 0.f, 0.f, 0.f};
    const int s_rd = (pl >> 1) & 3;

    #pragma unroll 1
    for (int half = 0; half < 2; ++half) {
        // ---- build 64 feature rows (1 pt per lane): 3 raw x rows + bias chunk ----
        {
            const int p = pt0 + half * 64 + lane;
            const int t = p >> 10, g = p & 1023;
            const float4* xr = (const float4*)x;
            const size_t r1 = ((size_t)(t - 1) * 1024 + g) * 2;
            const size_t r2 = ((size_t)(t - 2) * 1024 + g) * 2;
            const size_t r3 = ((size_t)(t - 3) * 1024 + g) * 2;
            float4 a0 = xr[r1], a1 = xr[r1 + 1];
            float4 b0 = xr[r2], b1 = xr[r2 + 1];
            float4 c0 = xr[r3], c1 = xr[r3 + 1];
            uint4 q0 = make_uint4(pk2(a0.x,a0.y), pk2(a0.z,a0.w), pk2(a1.x,a1.y), pk2(a1.z,a1.w));
            uint4 q1 = make_uint4(pk2(b0.x,b0.y), pk2(b0.z,b0.w), pk2(b1.x,b1.y), pk2(b1.z,b1.w));
            uint4 q2 = make_uint4(pk2(c0.x,c0.y), pk2(c0.z,c0.w), pk2(c1.x,c1.y), pk2(c1.z,c1.w));
            uint4 q3 = make_uint4(0x00003f80u, 0u, 0u, 0u);   // bf16 1.0 at k=24
            const int s = (lane >> 1) & 3;
            uint4* Frow = (uint4*)&F[w][lane][0];
            Frow[0 ^ s] = q0; Frow[1 ^ s] = q1; Frow[2 ^ s] = q2; Frow[3 ^ s] = q3;
        }
        asm volatile("s_waitcnt lgkmcnt(0)" ::: "memory");   // cross-lane LDS dep within wave
        __builtin_amdgcn_sched_barrier(0);

        #pragma unroll 2
        for (int rb = 0; rb < 4; ++rb) {
            const int m0 = pt0 + half * 64 + rb * 16;

            // B1-fragment: local F row rb*16+pl, k-chunk (c ^ swizzle)
            bf16x8 bf1 = *(bf16x8*)&F[w][rb*16 + pl][(c ^ s_rd) * 8];

            // ---- layer 1: D1 = W'' . X  (bias via k=24; rows sigma-permuted) ----
            f32x4 d1[4];
            #pragma unroll
            for (int T = 0; T < 4; ++T)
                d1[T] = __builtin_amdgcn_mfma_f32_16x16x32_bf16(wa[T], bf1, zero, 0, 0, 0);

            // relu + pack: registers ARE the layer-2 B-fragment (sigma trick; no LDS)
            BF8 bh0, bh1;
            bh0.u[0] = pk2(fmaxf(d1[0][0],0.f), fmaxf(d1[0][1],0.f));
            bh0.u[1] = pk2(fmaxf(d1[0][2],0.f), fmaxf(d1[0][3],0.f));
            bh0.u[2] = pk2(fmaxf(d1[1][0],0.f), fmaxf(d1[1][1],0.f));
            bh0.u[3] = pk2(fmaxf(d1[1][2],0.f), fmaxf(d1[1][3],0.f));
            bh1.u[0] = pk2(fmaxf(d1[2][0],0.f), fmaxf(d1[2][1],0.f));
            bh1.u[1] = pk2(fmaxf(d1[2][2],0.f), fmaxf(d1[2][3],0.f));
            bh1.u[2] = pk2(fmaxf(d1[3][0],0.f), fmaxf(d1[3][1],0.f));
            bh1.u[3] = pk2(fmaxf(d1[3][2],0.f), fmaxf(d1[3][3],0.f));

            // ---- layer 2 ----
            f32x4 d2[4];
            #pragma unroll
            for (int U = 0; U < 4; ++U) {
                d2[U] = __builtin_amdgcn_mfma_f32_16x16x32_bf16(wi[0][U], bh0.v, bias2[U], 0, 0, 0);
                d2[U] = __builtin_amdgcn_mfma_f32_16x16x32_bf16(wi[1][U], bh1.v, d2[U],   0, 0, 0);
            }

            // Pade(5,4) tanh, vectorized (v_pk_fma_f32 path); clamp = v_med3
            float part = 0.f;
            #pragma unroll
            for (int U = 0; U < 4; ++U) {
                f32x4 z;
                z[0] = __builtin_amdgcn_fmed3f(d2[U][0], -4.f, 4.f);
                z[1] = __builtin_amdgcn_fmed3f(d2[U][1], -4.f, 4.f);
                z[2] = __builtin_amdgcn_fmed3f(d2[U][2], -4.f, 4.f);
                z[3] = __builtin_amdgcn_fmed3f(d2[U][3], -4.f, 4.f);
                f32x4 p2  = z * z;
                f32x4 num = z * (p2 * (p2 + 105.f) + 945.f);
                f32x4 den = p2 * (p2 * 15.f + 420.f) + 945.f;
                #pragma unroll
                for (int j = 0; j < 4; ++j)
                    part = fmaf(wo[U][j], num[j] * __builtin_amdgcn_rcpf(den[j]), part);
            }
            // reduce across the 4 c-groups (same pt at lanes pl, pl+16, pl+32, pl+48)
            part += __shfl_xor(part, 16);
            part += __shfl_xor(part, 32);
            if (lane < 16)
                out[m0 + lane] = part + bout;
        }
    }
}

__global__ __launch_bounds__(256) void narx_pass(const float* __restrict__ x, float* __restrict__ out) {
    const int i = blockIdx.x * 256 + threadIdx.x;   // i < 3072
    out[i] = x[i * 8 + 7];
}

extern "C" void kernel_launch(void* const* d_in, const int* in_sizes, int n_in,
                              void* d_out, int out_size, void* d_ws, size_t ws_size,
                              hipStream_t stream) {
    const float* x     = (const float*)d_in[0];
    const float* W_in  = (const float*)d_in[1];
    const float* b_in  = (const float*)d_in[2];
    const float* W_ih  = (const float*)d_in[3];
    const float* b_ih  = (const float*)d_in[4];
    // d_in[5] = W_hh: unused in the reference forward
    const float* b_hh  = (const float*)d_in[6];
    const float* W_out = (const float*)d_in[7];
    const float* b_out = (const float*)d_in[8];
    float* out = (float*)d_out;
    uint4* ws = (uint4*)d_ws;            // needs 20.5 KB

    narx_prep<<<1, 64, 0, stream>>>(W_in, b_in, W_ih, b_ih, b_hh, W_out, ws);
    // points m in [3072, 4096*1024): 4,191,232 = 8186 blocks * 512 pts
    narx_main<<<8186, 256, 0, stream>>>(x, ws, b_out, out);
    narx_pass<<<12, 256, 0, stream>>>(x, out);      // t < 3 passthrough
}

// Round 10
// 133.562 us; speedup vs baseline: 1.7975x; 1.1249x over previous
//
#include <hip/hip_runtime.h>
#include <hip/hip_bf16.h>

// NARX forward via bf16 MFMA (16x16x32), round 10.
// R9 + three changes:
//  - asm-pinned weight fragments (kill per-tile ws reloads = ~4.2 GB L2 traffic)
//  - cross-half x-row prefetch into registers (hide global latency under tiles)
//  - packed-f32 ratio/wo-dot epilogue (-16 VALU inst/tile); F parity dbuf.

typedef __attribute__((ext_vector_type(8))) short bf16x8;
typedef __attribute__((ext_vector_type(4))) float f32x4;

__device__ __forceinline__ unsigned pk2(float lo, float hi) {
    __hip_bfloat162 h = __float22bfloat162_rn(float2{lo, hi});
    unsigned u; __builtin_memcpy(&u, &h, 4);   // v_cvt_pk_bf16_f32; memcpy is free
    return u;
}

union BF8 { bf16x8 v; unsigned u[4]; uint4 q; };

// d_ws layout in uint4 (16B) units:
//   [0,256)     WA[lane][T]      bf16x8  (folded W_in', sigma-permuted rows, bias col k=24)
//   [256,768)   WI[lane][k0][U]  bf16x8  (W_ih, natural)
//   [768,1024)  B2[lane][U]      float4  (b_ih + b_hh slice)
//   [1024,1280) WO[lane][U]      float4  (W_out slice)

__global__ __launch_bounds__(64) void narx_prep(
    const float* __restrict__ W_in, const float* __restrict__ b_in,
    const float* __restrict__ W_ih, const float* __restrict__ b_ih,
    const float* __restrict__ b_hh, const float* __restrict__ W_out,
    uint4* __restrict__ ws)
{
    const int lane = threadIdx.x;        // 64 threads, one wave
    const int c = lane >> 4, pl = lane & 15;

    // Folded W' (64x32): k0..7 = x[t-1] ch0..7, k8..15 = x[t-2], k16..23 = x[t-3],
    // k24 = bias (feature 1.0), k25..31 = 0.
    // Row permutation sigma: A-tile T, tile-row pl sources W_in row
    //   r = 8*(pl>>2) + (pl&3) + 4*(T&1) + 32*(T>>1)
    // so D1 reg (T,q) at lane c holds h_{8c + 4*(T&1) + q + 32*(T>>1)} =
    // exactly the layer-2 B-fragment (bh0 from T=0,1; bh1 from T=2,3).
    #pragma unroll
    for (int T = 0; T < 4; ++T) {
        const int r = ((pl >> 2) * 8) + (pl & 3) + (T & 1) * 4 + (T >> 1) * 32;
        const float* W = W_in + r * 32;
        float wr[8];
        if (c == 0) {
            #pragma unroll
            for (int j = 0; j < 7; ++j) wr[j] = W[j] + W[21 + j];
            wr[7] = W[28] + W[31];
        } else if (c == 1) {
            #pragma unroll
            for (int j = 0; j < 7; ++j) wr[j] = W[14 + j];
            wr[7] = W[30];
        } else if (c == 2) {
            #pragma unroll
            for (int j = 0; j < 7; ++j) wr[j] = W[7 + j];
            wr[7] = W[29];
        } else {
            wr[0] = b_in[r];
            #pragma unroll
            for (int j = 1; j < 8; ++j) wr[j] = 0.0f;
        }
        BF8 t;
        t.u[0] = pk2(wr[0], wr[1]); t.u[1] = pk2(wr[2], wr[3]);
        t.u[2] = pk2(wr[4], wr[5]); t.u[3] = pk2(wr[6], wr[7]);
        ws[lane*4 + T] = t.q;
    }

    // W_ih fragments (natural): A[row=16U+pl][k = 32*k0 + 8c + j]
    #pragma unroll
    for (int k0 = 0; k0 < 2; ++k0)
    #pragma unroll
    for (int U = 0; U < 4; ++U) {
        const float* p = W_ih + (16*U + pl) * 64 + 32*k0 + 8*c;
        float4 u0 = *(const float4*)p, u1 = *(const float4*)(p + 4);
        BF8 t;
        t.u[0] = pk2(u0.x, u0.y); t.u[1] = pk2(u0.z, u0.w);
        t.u[2] = pk2(u1.x, u1.y); t.u[3] = pk2(u1.z, u1.w);
        ws[256 + lane*8 + k0*4 + U] = t.q;
    }

    // bias2 / wo per-lane slices at h = 16U + 4c + q
    float4* wsf = (float4*)ws;
    #pragma unroll
    for (int U = 0; U < 4; ++U) {
        const int o = 16*U + 4*c;
        wsf[768  + lane*4 + U] = make_float4(b_ih[o+0]+b_hh[o+0], b_ih[o+1]+b_hh[o+1],
                                             b_ih[o+2]+b_hh[o+2], b_ih[o+3]+b_hh[o+3]);
        wsf[1024 + lane*4 + U] = make_float4(W_out[o+0], W_out[o+1], W_out[o+2], W_out[o+3]);
    }
}

__global__ __launch_bounds__(256, 3) void narx_main(
    const float* __restrict__ x, const uint4* __restrict__ ws,
    const float* __restrict__ b_out, float* __restrict__ out)
{
    // Per-wave F tile, parity double-buffered per half: 2 x 64 pts x 32 bf16.
    __shared__ unsigned short F[4][2][64][32];

    // bijective XCD-aware swizzle (m204)
    const int nwg  = gridDim.x;
    const int orig = blockIdx.x;
    const int q8 = nwg >> 3, r8 = nwg & 7;
    const int xcd = orig & 7, inner = orig >> 3;
    const int b = (xcd < r8 ? xcd * (q8 + 1) : r8 * (q8 + 1) + (xcd - r8) * q8) + inner;

    const int lane = threadIdx.x & 63;
    const int w    = threadIdx.x >> 6;
    const int c    = lane >> 4;
    const int pl   = lane & 15;
    const int pt0  = 3072 + b * 512 + w * 128;

    // ---- fragment loads (coalesced, L2-hot) ----
    bf16x8 wa[4];
    #pragma unroll
    for (int T = 0; T < 4; ++T) { BF8 t; t.q = ws[lane*4 + T]; wa[T] = t.v; }
    bf16x8 wi[2][4];
    #pragma unroll
    for (int k0 = 0; k0 < 2; ++k0)
    #pragma unroll
    for (int U = 0; U < 4; ++U) { BF8 t; t.q = ws[256 + lane*8 + k0*4 + U]; wi[k0][U] = t.v; }
    const float4* wsf = (const float4*)ws;
    f32x4 bias2[4], wo[4];
    #pragma unroll
    for (int U = 0; U < 4; ++U) {
        float4 v = wsf[768 + lane*4 + U];
        bias2[U] = f32x4{v.x, v.y, v.z, v.w};
        float4 u = wsf[1024 + lane*4 + U];
        wo[U] = f32x4{u.x, u.y, u.z, u.w};
    }
    // Pin invariants: opaque values cannot be rematerialized / reloaded per tile.
    asm volatile("" : "+v"(wa[0]), "+v"(wa[1]), "+v"(wa[2]), "+v"(wa[3]),
                      "+v"(wi[0][0]), "+v"(wi[0][1]), "+v"(wi[0][2]), "+v"(wi[0][3]),
                      "+v"(wi[1][0]), "+v"(wi[1][1]), "+v"(wi[1][2]), "+v"(wi[1][3]),
                      "+v"(bias2[0]), "+v"(bias2[1]), "+v"(bias2[2]), "+v"(bias2[3]),
                      "+v"(wo[0]), "+v"(wo[1]), "+v"(wo[2]), "+v"(wo[3]));

    const float bout = b_out[0];
    const f32x4 zero = {0.f, 0.f, 0.f, 0.f};
    const int s_rd = (pl >> 1) & 3;
    const float4* xr = (const float4*)x;

    // ---- prefetch half-0 x rows into registers ----
    float4 A0, A1, B0, B1, C0, C1;
    {
        const int p = pt0 + lane;
        const int t = p >> 10, g = p & 1023;
        const size_t r1 = ((size_t)(t - 1) * 1024 + g) * 2;
        const size_t r2 = ((size_t)(t - 2) * 1024 + g) * 2;
        const size_t r3 = ((size_t)(t - 3) * 1024 + g) * 2;
        A0 = xr[r1]; A1 = xr[r1 + 1];
        B0 = xr[r2]; B1 = xr[r2 + 1];
        C0 = xr[r3]; C1 = xr[r3 + 1];
    }

    #pragma unroll 1
    for (int half = 0; half < 2; ++half) {
        // ---- pack + write this half's F tile (consumes prefetched regs) ----
        {
            uint4 q0 = make_uint4(pk2(A0.x,A0.y), pk2(A0.z,A0.w), pk2(A1.x,A1.y), pk2(A1.z,A1.w));
            uint4 q1 = make_uint4(pk2(B0.x,B0.y), pk2(B0.z,B0.w), pk2(B1.x,B1.y), pk2(B1.z,B1.w));
            uint4 q2 = make_uint4(pk2(C0.x,C0.y), pk2(C0.z,C0.w), pk2(C1.x,C1.y), pk2(C1.z,C1.w));
            uint4 q3 = make_uint4(0x00003f80u, 0u, 0u, 0u);   // bf16 1.0 at k=24
            const int s = (lane >> 1) & 3;
            uint4* Frow = (uint4*)&F[w][half][lane][0];
            Frow[0 ^ s] = q0; Frow[1 ^ s] = q1; Frow[2 ^ s] = q2; Frow[3 ^ s] = q3;
        }
        // ---- issue next half's loads now; they fly under the tile loop.
        // (For half==1 the addresses are still in-bounds: max p -> t=4096, reads row 4095.)
        {
            const int p = pt0 + (half + 1) * 64 + lane;
            const int t = p >> 10, g = p & 1023;
            const size_t r1 = ((size_t)(t - 1) * 1024 + g) * 2;
            const size_t r2 = ((size_t)(t - 2) * 1024 + g) * 2;
            const size_t r3 = ((size_t)(t - 3) * 1024 + g) * 2;
            A0 = xr[r1]; A1 = xr[r1 + 1];
            B0 = xr[r2]; B1 = xr[r2 + 1];
            C0 = xr[r3]; C1 = xr[r3 + 1];
        }
        asm volatile("s_waitcnt lgkmcnt(0)" ::: "memory");   // F writes visible to wave
        __builtin_amdgcn_sched_barrier(0);

        #pragma unroll 2
        for (int rb = 0; rb < 4; ++rb) {
            const int m0 = pt0 + half * 64 + rb * 16;

            // B1-fragment: local F row rb*16+pl, k-chunk (c ^ swizzle)
            bf16x8 bf1 = *(bf16x8*)&F[w][half][rb*16 + pl][(c ^ s_rd) * 8];

            // ---- layer 1: D1 = W'' . X (bias via k=24; rows sigma-permuted) ----
            f32x4 d1[4];
            #pragma unroll
            for (int T = 0; T < 4; ++T)
                d1[T] = __builtin_amdgcn_mfma_f32_16x16x32_bf16(wa[T], bf1, zero, 0, 0, 0);

            // relu + pack: registers ARE the layer-2 B-fragment (sigma trick)
            BF8 bh0, bh1;
            bh0.u[0] = pk2(fmaxf(d1[0][0],0.f), fmaxf(d1[0][1],0.f));
            bh0.u[1] = pk2(fmaxf(d1[0][2],0.f), fmaxf(d1[0][3],0.f));
            bh0.u[2] = pk2(fmaxf(d1[1][0],0.f), fmaxf(d1[1][1],0.f));
            bh0.u[3] = pk2(fmaxf(d1[1][2],0.f), fmaxf(d1[1][3],0.f));
            bh1.u[0] = pk2(fmaxf(d1[2][0],0.f), fmaxf(d1[2][1],0.f));
            bh1.u[1] = pk2(fmaxf(d1[2][2],0.f), fmaxf(d1[2][3],0.f));
            bh1.u[2] = pk2(fmaxf(d1[3][0],0.f), fmaxf(d1[3][1],0.f));
            bh1.u[3] = pk2(fmaxf(d1[3][2],0.f), fmaxf(d1[3][3],0.f));

            // ---- layer 2 ----
            f32x4 d2[4];
            #pragma unroll
            for (int U = 0; U < 4; ++U) {
                d2[U] = __builtin_amdgcn_mfma_f32_16x16x32_bf16(wi[0][U], bh0.v, bias2[U], 0, 0, 0);
                d2[U] = __builtin_amdgcn_mfma_f32_16x16x32_bf16(wi[1][U], bh1.v, d2[U],   0, 0, 0);
            }

            // Pade(5,4) tanh (clamp +-4 via med3) + packed wo-dot accumulation
            f32x4 pacc = zero;
            #pragma unroll
            for (int U = 0; U < 4; ++U) {
                f32x4 z;
                z[0] = __builtin_amdgcn_fmed3f(d2[U][0], -4.f, 4.f);
                z[1] = __builtin_amdgcn_fmed3f(d2[U][1], -4.f, 4.f);
                z[2] = __builtin_amdgcn_fmed3f(d2[U][2], -4.f, 4.f);
                z[3] = __builtin_amdgcn_fmed3f(d2[U][3], -4.f, 4.f);
                f32x4 p2  = z * z;
                f32x4 num = z * (p2 * (p2 + 105.f) + 945.f);
                f32x4 den = p2 * (p2 * 15.f + 420.f) + 945.f;
                f32x4 r;
                r[0] = __builtin_amdgcn_rcpf(den[0]);
                r[1] = __builtin_amdgcn_rcpf(den[1]);
                r[2] = __builtin_amdgcn_rcpf(den[2]);
                r[3] = __builtin_amdgcn_rcpf(den[3]);
                pacc += wo[U] * (num * r);          // v_pk_fma_f32 path
            }
            float part = (pacc[0] + pacc[1]) + (pacc[2] + pacc[3]);
            // reduce across the 4 c-groups (same pt at lanes pl, pl+16, pl+32, pl+48)
            part += __shfl_xor(part, 16);
            part += __shfl_xor(part, 32);
            if (lane < 16)
                out[m0 + lane] = part + bout;
        }
    }
}

__global__ __launch_bounds__(256) void narx_pass(const float* __restrict__ x, float* __restrict__ out) {
    const int i = blockIdx.x * 256 + threadIdx.x;   // i < 3072
    out[i] = x[i * 8 + 7];
}

extern "C" void kernel_launch(void* const* d_in, const int* in_sizes, int n_in,
                              void* d_out, int out_size, void* d_ws, size_t ws_size,
                              hipStream_t stream) {
    const float* x     = (const float*)d_in[0];
    const float* W_in  = (const float*)d_in[1];
    const float* b_in  = (const float*)d_in[2];
    const float* W_ih  = (const float*)d_in[3];
    const float* b_ih  = (const float*)d_in[4];
    // d_in[5] = W_hh: unused in the reference forward
    const float* b_hh  = (const float*)d_in[6];
    const float* W_out = (const float*)d_in[7];
    const float* b_out = (const float*)d_in[8];
    float* out = (float*)d_out;
    uint4* ws = (uint4*)d_ws;            // needs 20.5 KB

    narx_prep<<<1, 64, 0, stream>>>(W_in, b_in, W_ih, b_ih, b_hh, W_out, ws);
    // points m in [3072, 4096*1024): 4,191,232 = 8186 blocks * 512 pts
    narx_main<<<8186, 256, 0, stream>>>(x, ws, b_out, out);
    narx_pass<<<12, 256, 0, stream>>>(x, out);      // t < 3 passthrough
}

// Round 11
// 128.814 us; speedup vs baseline: 1.8637x; 1.0369x over previous
//
#include <hip/hip_runtime.h>
#include <hip/hip_bf16.h>

// NARX forward via bf16 MFMA (16x16x32), round 11.
// Chain-shortening round:
//  - y = W_out . a computed by a 3rd MFMA (W_ih rows sigma-permuted so d2 regs
//    ARE its B-fragment; A row0 = W_out, C row0 = b_out). Removes both
//    shfl_xor + lgkm waits from every tile's critical path.
//  - Both F halves built once at wave start (single LDS drain per kernel);
//    tile loop is read-only LDS + register dataflow, next-tile bf1 hoisted.
//  - Invariant fragments pinned; launch_bounds(256,2); LDS caps occupancy.

typedef __attribute__((ext_vector_type(8))) short bf16x8;
typedef __attribute__((ext_vector_type(4))) float f32x4;

__device__ __forceinline__ unsigned pk2(float lo, float hi) {
    __hip_bfloat162 h = __float22bfloat162_rn(float2{lo, hi});
    unsigned u; __builtin_memcpy(&u, &h, 4);   // v_cvt_pk_bf16_f32; memcpy is free
    return u;
}

union BF8 { bf16x8 v; unsigned u[4]; uint4 q; };

// d_ws layout in uint4 (16B) units:
//   [0,256)     WA[lane][T]      bf16x8  (folded W_in', sigma rows, bias col k=24)
//   [256,768)   WI[lane][k0][U]  bf16x8  (W_ih, sigma-permuted ROWS, natural k)
//   [768,1024)  B2[lane][U]      float4  (b_ih+b_hh, sigma-sliced)
//   [1280,1408) WOA[lane][k0]    bf16x8  (y-MFMA A-frag: row0 = W_out, rows1-15 = 0)

__global__ __launch_bounds__(64) void narx_prep(
    const float* __restrict__ W_in, const float* __restrict__ b_in,
    const float* __restrict__ W_ih, const float* __restrict__ b_ih,
    const float* __restrict__ b_hh, const float* __restrict__ W_out,
    uint4* __restrict__ ws)
{
    const int lane = threadIdx.x;        // 64 threads, one wave
    const int c = lane >> 4, pl = lane & 15;

    // ---- layer-1 A-fragments: folded W' (64x32), sigma rows, bias col k=24 ----
    // sigma: tile T, tile-row pl sources W_in row 8*(pl>>2)+(pl&3)+4*(T&1)+32*(T>>1)
    // so d1 reg (T,q) at lane c holds h_{8c + 4*(T&1) + q + 32*(T>>1)}.
    #pragma unroll
    for (int T = 0; T < 4; ++T) {
        const int r = ((pl >> 2) * 8) + (pl & 3) + (T & 1) * 4 + (T >> 1) * 32;
        const float* W = W_in + r * 32;
        float wr[8];
        if (c == 0) {
            #pragma unroll
            for (int j = 0; j < 7; ++j) wr[j] = W[j] + W[21 + j];
            wr[7] = W[28] + W[31];
        } else if (c == 1) {
            #pragma unroll
            for (int j = 0; j < 7; ++j) wr[j] = W[14 + j];
            wr[7] = W[30];
        } else if (c == 2) {
            #pragma unroll
            for (int j = 0; j < 7; ++j) wr[j] = W[7 + j];
            wr[7] = W[29];
        } else {
            wr[0] = b_in[r];
            #pragma unroll
            for (int j = 1; j < 8; ++j) wr[j] = 0.0f;
        }
        BF8 t;
        t.u[0] = pk2(wr[0], wr[1]); t.u[1] = pk2(wr[2], wr[3]);
        t.u[2] = pk2(wr[4], wr[5]); t.u[3] = pk2(wr[6], wr[7]);
        ws[lane*4 + T] = t.q;
    }

    // ---- layer-2 A-fragments: SAME sigma on W_ih rows, natural k columns ----
    // d2 reg (U,q) at lane c then holds a_{8c + 4*(U&1) + q + 32*(U>>1)}:
    // exactly the y-MFMA B-fragment after pairing (U=0,1 -> pb0; U=2,3 -> pb1).
    #pragma unroll
    for (int k0 = 0; k0 < 2; ++k0)
    #pragma unroll
    for (int U = 0; U < 4; ++U) {
        const int r = ((pl >> 2) * 8) + (pl & 3) + (U & 1) * 4 + (U >> 1) * 32;
        const float* p = W_ih + r * 64 + 32*k0 + 8*c;
        float4 u0 = *(const float4*)p, u1 = *(const float4*)(p + 4);
        BF8 t;
        t.u[0] = pk2(u0.x, u0.y); t.u[1] = pk2(u0.z, u0.w);
        t.u[2] = pk2(u1.x, u1.y); t.u[3] = pk2(u1.z, u1.w);
        ws[256 + lane*8 + k0*4 + U] = t.q;
    }

    // ---- bias2 sigma-sliced: reg q of tile U at lane c = bias[8c + q + 4*(U&1) + 32*(U>>1)] ----
    float* bsum = (float*)&ws[1536];     // scratch (unused later)
    if (lane < 64) { /* all lanes */ }
    float4* wsf = (float4*)ws;
    #pragma unroll
    for (int U = 0; U < 4; ++U) {
        const int o = 8*c + 4*(U & 1) + 32*(U >> 1);
        wsf[768 + lane*4 + U] = make_float4(b_ih[o+0]+b_hh[o+0], b_ih[o+1]+b_hh[o+1],
                                            b_ih[o+2]+b_hh[o+2], b_ih[o+3]+b_hh[o+3]);
    }
    (void)bsum;

    // ---- y-MFMA A-fragments: A[row=pl][k=32k0+8c+j] = (pl==0 ? W_out[k] : 0) ----
    #pragma unroll
    for (int k0 = 0; k0 < 2; ++k0) {
        BF8 t;
        if (pl == 0) {
            const float* p = W_out + 32*k0 + 8*c;
            t.u[0] = pk2(p[0], p[1]); t.u[1] = pk2(p[2], p[3]);
            t.u[2] = pk2(p[4], p[5]); t.u[3] = pk2(p[6], p[7]);
        } else {
            t.u[0] = t.u[1] = t.u[2] = t.u[3] = 0u;
        }
        ws[1280 + lane*2 + k0] = t.q;
    }
}

__global__ __launch_bounds__(256, 2) void narx_main(
    const float* __restrict__ x, const uint4* __restrict__ ws,
    const float* __restrict__ b_out, float* __restrict__ out)
{
    // Per-wave F tile: 128 pts x 32 bf16, 16B-chunk XOR swizzle. Written ONCE.
    __shared__ unsigned short F[4][128][32];

    // bijective XCD-aware swizzle (m204)
    const int nwg  = gridDim.x;
    const int orig = blockIdx.x;
    const int q8 = nwg >> 3, r8 = nwg & 7;
    const int xcd = orig & 7, inner = orig >> 3;
    const int b = (xcd < r8 ? xcd * (q8 + 1) : r8 * (q8 + 1) + (xcd - r8) * q8) + inner;

    const int lane = threadIdx.x & 63;
    const int w    = threadIdx.x >> 6;
    const int c    = lane >> 4;
    const int pl   = lane & 15;
    const int pt0  = 3072 + b * 512 + w * 128;

    // ---- fragment loads (coalesced, L2-hot) ----
    bf16x8 wa[4];
    #pragma unroll
    for (int T = 0; T < 4; ++T) { BF8 t; t.q = ws[lane*4 + T]; wa[T] = t.v; }
    bf16x8 wi[2][4];
    #pragma unroll
    for (int k0 = 0; k0 < 2; ++k0)
    #pragma unroll
    for (int U = 0; U < 4; ++U) { BF8 t; t.q = ws[256 + lane*8 + k0*4 + U]; wi[k0][U] = t.v; }
    bf16x8 woa[2];
    #pragma unroll
    for (int k0 = 0; k0 < 2; ++k0) { BF8 t; t.q = ws[1280 + lane*2 + k0]; woa[k0] = t.v; }
    const float4* wsf = (const float4*)ws;
    f32x4 bias2[4];
    #pragma unroll
    for (int U = 0; U < 4; ++U) {
        float4 v = wsf[768 + lane*4 + U];
        bias2[U] = f32x4{v.x, v.y, v.z, v.w};
    }
    const float bout = b_out[0];
    const f32x4 cy = {c == 0 ? bout : 0.f, 0.f, 0.f, 0.f};   // y-MFMA C (row0 = b_out)
    const f32x4 zero = {0.f, 0.f, 0.f, 0.f};

    // ---- build BOTH F halves up front (12 loads -> pack -> 8 LDS writes) ----
    const float4* xr = (const float4*)x;
    {
        const int p0 = pt0 + lane, p1 = pt0 + 64 + lane;
        const int t0 = p0 >> 10, g0v = p0 & 1023;
        const int t1 = p1 >> 10, g1v = p1 & 1023;
        const size_t a1 = ((size_t)(t0-1)*1024 + g0v)*2, a2 = ((size_t)(t0-2)*1024 + g0v)*2,
                     a3 = ((size_t)(t0-3)*1024 + g0v)*2;
        const size_t d1a = ((size_t)(t1-1)*1024 + g1v)*2, d2a = ((size_t)(t1-2)*1024 + g1v)*2,
                     d3a = ((size_t)(t1-3)*1024 + g1v)*2;
        float4 A0 = xr[a1],  A1 = xr[a1+1],  B0 = xr[a2],  B1 = xr[a2+1],
               C0 = xr[a3],  C1 = xr[a3+1];
        float4 D0 = xr[d1a], D1 = xr[d1a+1], E0 = xr[d2a], E1 = xr[d2a+1],
               G0 = xr[d3a], G1 = xr[d3a+1];
        const int s = (lane >> 1) & 3;
        uint4* Fr0 = (uint4*)&F[w][lane][0];
        Fr0[0 ^ s] = make_uint4(pk2(A0.x,A0.y), pk2(A0.z,A0.w), pk2(A1.x,A1.y), pk2(A1.z,A1.w));
        Fr0[1 ^ s] = make_uint4(pk2(B0.x,B0.y), pk2(B0.z,B0.w), pk2(B1.x,B1.y), pk2(B1.z,B1.w));
        Fr0[2 ^ s] = make_uint4(pk2(C0.x,C0.y), pk2(C0.z,C0.w), pk2(C1.x,C1.y), pk2(C1.z,C1.w));
        Fr0[3 ^ s] = make_uint4(0x00003f80u, 0u, 0u, 0u);
        uint4* Fr1 = (uint4*)&F[w][64 + lane][0];   // same swizzle key: (64+lane)>>1 & 3 == s
        Fr1[0 ^ s] = make_uint4(pk2(D0.x,D0.y), pk2(D0.z,D0.w), pk2(D1.x,D1.y), pk2(D1.z,D1.w));
        Fr1[1 ^ s] = make_uint4(pk2(E0.x,E0.y), pk2(E0.z,E0.w), pk2(E1.x,E1.y), pk2(E1.z,E1.w));
        Fr1[2 ^ s] = make_uint4(pk2(G0.x,G0.y), pk2(G0.z,G0.w), pk2(G1.x,G1.y), pk2(G1.z,G1.w));
        Fr1[3 ^ s] = make_uint4(0x00003f80u, 0u, 0u, 0u);
    }
    asm volatile("s_waitcnt lgkmcnt(0)" ::: "memory");   // cross-lane LDS dep within wave
    __builtin_amdgcn_sched_barrier(0);

    // Pin invariants after staging (opaque -> not rematerializable).
    asm volatile("" : "+v"(wa[0]), "+v"(wa[1]), "+v"(wa[2]), "+v"(wa[3]),
                      "+v"(wi[0][0]), "+v"(wi[0][1]), "+v"(wi[0][2]), "+v"(wi[0][3]),
                      "+v"(wi[1][0]), "+v"(wi[1][1]), "+v"(wi[1][2]), "+v"(wi[1][3]),
                      "+v"(bias2[0]), "+v"(bias2[1]), "+v"(bias2[2]), "+v"(bias2[3]),
                      "+v"(woa[0]), "+v"(woa[1]));

    const int s_rd = (pl >> 1) & 3;
    // hoisted first-tile B1 fragment
    bf16x8 bf1 = *(bf16x8*)&F[w][pl][(c ^ s_rd) * 8];

    #pragma unroll 2
    for (int rb = 0; rb < 8; ++rb) {
        const int m0 = pt0 + rb * 16;

        // ---- layer 1: D1 = W'' . X ----
        f32x4 d1[4];
        #pragma unroll
        for (int T = 0; T < 4; ++T)
            d1[T] = __builtin_amdgcn_mfma_f32_16x16x32_bf16(wa[T], bf1, zero, 0, 0, 0);

        // prefetch next tile's B1 while layer-1 MFMAs are in flight
        {
            const int rn = (rb < 7) ? rb + 1 : 7;
            bf1 = *(bf16x8*)&F[w][rn*16 + pl][(c ^ s_rd) * 8];
        }

        // relu + pack: regs ARE the layer-2 B-fragment (sigma)
        BF8 bh0, bh1;
        bh0.u[0] = pk2(fmaxf(d1[0][0],0.f), fmaxf(d1[0][1],0.f));
        bh0.u[1] = pk2(fmaxf(d1[0][2],0.f), fmaxf(d1[0][3],0.f));
        bh0.u[2] = pk2(fmaxf(d1[1][0],0.f), fmaxf(d1[1][1],0.f));
        bh0.u[3] = pk2(fmaxf(d1[1][2],0.f), fmaxf(d1[1][3],0.f));
        bh1.u[0] = pk2(fmaxf(d1[2][0],0.f), fmaxf(d1[2][1],0.f));
        bh1.u[1] = pk2(fmaxf(d1[2][2],0.f), fmaxf(d1[2][3],0.f));
        bh1.u[2] = pk2(fmaxf(d1[3][0],0.f), fmaxf(d1[3][1],0.f));
        bh1.u[3] = pk2(fmaxf(d1[3][2],0.f), fmaxf(d1[3][3],0.f));

        // ---- layer 2 (sigma-permuted rows) ----
        f32x4 d2[4];
        #pragma unroll
        for (int U = 0; U < 4; ++U) {
            d2[U] = __builtin_amdgcn_mfma_f32_16x16x32_bf16(wi[0][U], bh0.v, bias2[U], 0, 0, 0);
            d2[U] = __builtin_amdgcn_mfma_f32_16x16x32_bf16(wi[1][U], bh1.v, d2[U],   0, 0, 0);
        }

        // ---- tanh Pade(5,4), then pack a -> y-MFMA B-fragment ----
        f32x4 av[4];
        #pragma unroll
        for (int U = 0; U < 4; ++U) {
            f32x4 z;
            z[0] = __builtin_amdgcn_fmed3f(d2[U][0], -4.f, 4.f);
            z[1] = __builtin_amdgcn_fmed3f(d2[U][1], -4.f, 4.f);
            z[2] = __builtin_amdgcn_fmed3f(d2[U][2], -4.f, 4.f);
            z[3] = __builtin_amdgcn_fmed3f(d2[U][3], -4.f, 4.f);
            f32x4 p2  = z * z;
            f32x4 num = z * (p2 * (p2 + 105.f) + 945.f);
            f32x4 den = p2 * (p2 * 15.f + 420.f) + 945.f;
            f32x4 r;
            r[0] = __builtin_amdgcn_rcpf(den[0]);
            r[1] = __builtin_amdgcn_rcpf(den[1]);
            r[2] = __builtin_amdgcn_rcpf(den[2]);
            r[3] = __builtin_amdgcn_rcpf(den[3]);
            av[U] = num * r;
        }
        BF8 pb0, pb1;
        pb0.u[0] = pk2(av[0][0], av[0][1]); pb0.u[1] = pk2(av[0][2], av[0][3]);
        pb0.u[2] = pk2(av[1][0], av[1][1]); pb0.u[3] = pk2(av[1][2], av[1][3]);
        pb1.u[0] = pk2(av[2][0], av[2][1]); pb1.u[1] = pk2(av[2][2], av[2][3]);
        pb1.u[2] = pk2(av[3][0], av[3][1]); pb1.u[3] = pk2(av[3][2], av[3][3]);

        // ---- layer 3: y row0 = W_out . a + b_out (single D row used) ----
        f32x4 dy;
        dy = __builtin_amdgcn_mfma_f32_16x16x32_bf16(woa[0], pb0.v, cy, 0, 0, 0);
        dy = __builtin_amdgcn_mfma_f32_16x16x32_bf16(woa[1], pb1.v, dy, 0, 0, 0);

        if (lane < 16)
            out[m0 + lane] = dy[0];
    }
}

__global__ __launch_bounds__(256) void narx_pass(const float* __restrict__ x, float* __restrict__ out) {
    const int i = blockIdx.x * 256 + threadIdx.x;   // i < 3072
    out[i] = x[i * 8 + 7];
}

extern "C" void kernel_launch(void* const* d_in, const int* in_sizes, int n_in,
                              void* d_out, int out_size, void* d_ws, size_t ws_size,
                              hipStream_t stream) {
    const float* x     = (const float*)d_in[0];
    const float* W_in  = (const float*)d_in[1];
    const float* b_in  = (const float*)d_in[2];
    const float* W_ih  = (const float*)d_in[3];
    const float* b_ih  = (const float*)d_in[4];
    // d_in[5] = W_hh: unused in the reference forward
    const float* b_hh  = (const float*)d_in[6];
    const float* W_out = (const float*)d_in[7];
    const float* b_out = (const float*)d_in[8];
    float* out = (float*)d_out;
    uint4* ws = (uint4*)d_ws;            // needs ~24 KB

    narx_prep<<<1, 64, 0, stream>>>(W_in, b_in, W_ih, b_ih, b_hh, W_out, ws);
    // points m in [3072, 4096*1024): 4,191,232 = 8186 blocks * 512 pts
    narx_main<<<8186, 256, 0, stream>>>(x, ws, b_out, out);
    narx_pass<<<12, 256, 0, stream>>>(x, out);      // t < 3 passthrough
}